// Round 1
// 444.784 us; speedup vs baseline: 1.0250x; 1.0250x over previous
//
#include <hip/hip_runtime.h>
#include <hip/hip_bf16.h>

#define B_ 4
#define N_ 4096
#define C_ 64
#define R_ 16
#define EPS_ 1e-12f

typedef __attribute__((ext_vector_type(8))) short bf16x8;
typedef __attribute__((ext_vector_type(4))) float f32x4;

static __device__ __forceinline__ unsigned short f2bf(float f) {
    unsigned int u = __float_as_uint(f);
    unsigned int r = (u + 0x7fffu + ((u >> 16) & 1u)) >> 16;
    return (unsigned short)r;
}
static __device__ __forceinline__ float bf2f(unsigned short us) {
    return __uint_as_float(((unsigned int)us) << 16);
}

// K0f fragment layout: [b][rowtile=row/16][k32=k/32][fq=(k/8)&3][fr=row&15][e=k&7]
// One wave's A fragment for (rowtile,k32) = contiguous 1 KiB, lane l at +l*16B.
static __device__ __forceinline__ size_t k0f_off(int b, int rt, int k32, int fq, int fr) {
    return ((((size_t)(b * 256 + rt)) * 128 + k32) * 4 + fq) * 128 + fr * 8;
}

// Pass 1: tile pair (ti<=tj): K0 = 0.5*(W+W^T)*sigmoid(U U^T), write both
// orientations in MFMA-fragment layout, deg row sums via shfl + atomics.
__global__ __launch_bounds__(256) void k_pass1(
    const float* __restrict__ W, const float* __restrict__ U,
    unsigned short* __restrict__ K0, float* __restrict__ deg)
{
    const int tj = blockIdx.x, ti = blockIdx.y;
    if (ti > tj) return;
    const int I = ti * 64, J = tj * 64;
    const bool diag = (ti == tj);
    const int t = threadIdx.x;
    const int ii = t >> 2, g = t & 3, jjg = g * 16;

    __shared__ float UJ[64][17];
    __shared__ float Wc[64][65];
    __shared__ __align__(16) unsigned short K0s[64][72];

    {
        const float4 v = *(const float4*)(U + (size_t)(J + (t >> 2)) * R_ + (t & 3) * 4);
        UJ[t >> 2][(t & 3) * 4 + 0] = v.x;
        UJ[t >> 2][(t & 3) * 4 + 1] = v.y;
        UJ[t >> 2][(t & 3) * 4 + 2] = v.z;
        UJ[t >> 2][(t & 3) * 4 + 3] = v.w;
    }

    float4 wcv[4], wrv[4], wcvN[4], wrvN[4];
    #pragma unroll
    for (int k = 0; k < 4; k++) {
        const int idx = t + 256 * k, row = idx >> 4, c4 = idx & 15;
        wcv[k] = *(const float4*)(W + ((size_t)(0 * N_ + J + row)) * N_ + I + c4 * 4);
    }
    #pragma unroll
    for (int h = 0; h < 4; h++)
        wrv[h] = *(const float4*)(W + ((size_t)(0 * N_ + I + ii)) * N_ + J + jjg + 4 * h);

    float ui[16];
    {
        const float* up = U + (size_t)(I + ii) * R_;
        #pragma unroll
        for (int h = 0; h < 4; h++) {
            float4 v = *(const float4*)(up + 4 * h);
            ui[4*h] = v.x; ui[4*h+1] = v.y; ui[4*h+2] = v.z; ui[4*h+3] = v.w;
        }
    }
    __syncthreads(); // UJ ready

    float a[16];
    #pragma unroll
    for (int q = 0; q < 16; q++) {
        float s = 0.f;
        #pragma unroll
        for (int k = 0; k < 16; k++) s += ui[k] * UJ[jjg + q][k];
        a[q] = 1.0f / (1.0f + __expf(-s));
    }

    #pragma unroll
    for (int k = 0; k < 4; k++) {
        const int idx = t + 256 * k, row = idx >> 4, c4 = idx & 15;
        Wc[row][c4*4+0] = wcv[k].x; Wc[row][c4*4+1] = wcv[k].y;
        Wc[row][c4*4+2] = wcv[k].z; Wc[row][c4*4+3] = wcv[k].w;
    }
    __syncthreads(); // Wc ready for b=0

    for (int b = 0; b < B_; b++) {
        if (b < B_ - 1) {
            #pragma unroll
            for (int k = 0; k < 4; k++) {
                const int idx = t + 256 * k, row = idx >> 4, c4 = idx & 15;
                wcvN[k] = *(const float4*)(W + ((size_t)((b+1) * N_ + J + row)) * N_ + I + c4 * 4);
            }
            #pragma unroll
            for (int h = 0; h < 4; h++)
                wrvN[h] = *(const float4*)(W + ((size_t)((b+1) * N_ + I + ii)) * N_ + J + jjg + 4 * h);
        }

        const float* wrf = (const float*)wrv;
        float sumI = 0.f;
        unsigned int pk[8];
        #pragma unroll
        for (int q = 0; q < 16; q++) {
            float k0 = 0.5f * (wrf[q] + Wc[jjg + q][ii]) * a[q];
            sumI += k0;
            unsigned short us = f2bf(k0);
            if (q & 1) pk[q >> 1] |= ((unsigned int)us) << 16;
            else       pk[q >> 1] = us;
        }
        *(int4*)(&K0s[ii][jjg])     = make_int4(pk[0], pk[1], pk[2], pk[3]);
        *(int4*)(&K0s[ii][jjg + 8]) = make_int4(pk[4], pk[5], pk[6], pk[7]);
        // row-orientation fragment store: row I+ii, k = J+g*16 .. +15
        {
            const int rt  = (I + ii) >> 4, fr = ii & 15;
            const int k32 = (J >> 5) + (g >> 1), fqa = (g & 1) * 2;
            unsigned short* dst = K0 + k0f_off(b, rt, k32, fqa, fr);
            *(int4*)(dst)       = make_int4(pk[0], pk[1], pk[2], pk[3]);
            *(int4*)(dst + 128) = make_int4(pk[4], pk[5], pk[6], pk[7]);
        }
        {
            float s = sumI + __shfl_xor(sumI, 1, 64);
            s += __shfl_xor(s, 2, 64);
            if (g == 0) atomicAdd(deg + b * N_ + I + ii, s);
        }
        __syncthreads(); // K0s ready; Wc reads done

        if (!diag) {
            const int c2 = t & 31, r8 = t >> 5; // cols j=2c2,2c2+1; rows i=r8*8..+7
            unsigned int v[8];
            float cs0 = 0.f, cs1 = 0.f;
            #pragma unroll
            for (int k = 0; k < 8; k++) {
                v[k] = *(const unsigned int*)(&K0s[r8 * 8 + k][c2 * 2]);
                cs0 += bf2f((unsigned short)(v[k] & 0xffffu));
                cs1 += bf2f((unsigned short)(v[k] >> 16));
            }
            unsigned int plo[4], phi[4];
            #pragma unroll
            for (int m = 0; m < 4; m++) {
                plo[m] = (v[2*m] & 0xffffu) | (v[2*m+1] << 16);
                phi[m] = (v[2*m] >> 16) | (v[2*m+1] & 0xffff0000u);
            }
            // transposed fragment store: out row J+2c2(+1), k = I+r8*8 .. +7
            const int rtp  = (J >> 4) + (c2 >> 3), fr0 = (2 * c2) & 15;
            const int k32p = (I >> 5) + (r8 >> 2), fqp = r8 & 3;
            unsigned short* dst0 = K0 + k0f_off(b, rtp, k32p, fqp, fr0);
            *(int4*)(dst0)     = make_int4(plo[0], plo[1], plo[2], plo[3]);
            *(int4*)(dst0 + 8) = make_int4(phi[0], phi[1], phi[2], phi[3]);
            cs0 += __shfl_xor(cs0, 32, 64);
            cs1 += __shfl_xor(cs1, 32, 64);
            if ((t & 32) == 0) {
                atomicAdd(deg + b * N_ + J + 2 * c2,     cs0);
                atomicAdd(deg + b * N_ + J + 2 * c2 + 1, cs1);
            }
        }
        if (b < B_ - 1) {
            #pragma unroll
            for (int k = 0; k < 4; k++) {
                const int idx = t + 256 * k, row = idx >> 4, c4 = idx & 15;
                Wc[row][c4*4+0] = wcvN[k].x; Wc[row][c4*4+1] = wcvN[k].y;
                Wc[row][c4*4+2] = wcvN[k].z; Wc[row][c4*4+3] = wcvN[k].w;
            }
            #pragma unroll
            for (int h = 0; h < 4; h++) wrv[h] = wrvN[h];
            __syncthreads(); // Wc ready; K0s reads done
        }
    }
}

// xdTf fragment layout: [b][k32=j/32][cg=c/16][fq=(j/8)&3][fr=c&15][e=j&7]
// value = bf16( x[b,j,c] * rsqrt(deg[b,j]) )
__global__ __launch_bounds__(256) void k_xdT(
    const float* __restrict__ x, const float* __restrict__ deg,
    unsigned short* __restrict__ xdT)
{
    const int jt = blockIdx.x, b = blockIdx.y;
    const int J = jt * 64, t = threadIdx.x;
    __shared__ float xt[64][69];
    #pragma unroll
    for (int k = 0; k < 4; k++) {
        int idx = t + 256 * k;
        int row = idx >> 4, f4 = idx & 15;
        float d = rsqrtf(fmaxf(deg[b * N_ + J + row], EPS_));
        float4 v = *(const float4*)(x + ((size_t)(b * N_ + J + row)) * C_ + f4 * 4);
        xt[row][f4*4+0] = v.x * d; xt[row][f4*4+1] = v.y * d;
        xt[row][f4*4+2] = v.z * d; xt[row][f4*4+3] = v.w * d;
    }
    __syncthreads();
    #pragma unroll
    for (int p = 0; p < 2; p++) {
        const int linear = p * 256 + t;
        const int k32h = linear >> 8, rem = linear & 255;
        const int cg = rem >> 6, l = rem & 63, fq = l >> 4, fr = l & 15;
        const int c = cg * 16 + fr;
        const int jb = k32h * 32 + fq * 8;
        unsigned int pk[4];
        #pragma unroll
        for (int m = 0; m < 4; m++) {
            pk[m] = (unsigned int)f2bf(xt[jb + 2*m][c]) |
                    ((unsigned int)f2bf(xt[jb + 2*m + 1][c]) << 16);
        }
        unsigned short* dst = xdT +
            (((size_t)(b * 128 + (J >> 5) + k32h)) * 4 + cg) * 512 + l * 8;
        *(int4*)dst = make_int4(pk[0], pk[1], pk[2], pk[3]);
    }
}

// Async 16B global->LDS. LDS dest is wave-uniform base; HW appends lane*16.
static __device__ __forceinline__ void gll16(const unsigned short* g, const unsigned short* l) {
    __builtin_amdgcn_global_load_lds(
        (const __attribute__((address_space(1))) unsigned int*)g,
        (__attribute__((address_space(3))) unsigned int*)l,
        16, 0, 0);
}

// Pass 2 (rewritten): cooperative 256-thread block, M=32 rows x N=64 cols,
// full K=4096 per block (no split-K, no atomics, no out memset).
// A (2 rowtile-frags) and B (4 cg-frags) staged via global_load_lds into a
// double-buffered LDS pipeline, counted s_waitcnt vmcnt(6) (never drained
// mid-loop), raw s_barrier (avoids __syncthreads' vmcnt(0) drain).
// Per buffer: 4 k32-chunks -> 24 x 1KiB fragments = 6 global_load_lds/wave.
// Wave w: rows rt0+(w&1), cols ((w>>1)*2)*16 .. +32 (2 accs).
__global__ __launch_bounds__(256, 2) void k_gemm(
    const unsigned short* __restrict__ K0, const unsigned short* __restrict__ xdT,
    const float* __restrict__ deg, const float* __restrict__ wsc_p,
    float* __restrict__ out)
{
    const int mg = blockIdx.x, b = blockIdx.y;
    const int t = threadIdx.x, w = t >> 6, lane = t & 63;
    const int rt0 = mg * 2;
    const int rtl = w & 1, cgp = (w >> 1) * 2;
    const int fq = lane >> 4, fr = lane & 15;
    const int rt = rt0 + rtl;

    __shared__ __align__(16) unsigned short As[2 * 8 * 512];   // [buf][rtl*4+c][512]
    __shared__ __align__(16) unsigned short Bs[2 * 16 * 512];  // [buf][c*4+cg][512]

    // Preload every non-staging VMEM value BEFORE the pipeline so vmcnt
    // counts only global_load_lds ops inside the loop.
    const float wsc = wsc_p[0];
    float dsc[4];
    #pragma unroll
    for (int r = 0; r < 4; r++)
        dsc[r] = wsc * rsqrtf(fmaxf(deg[b * N_ + rt * 16 + fq * 4 + r], EPS_));

    // 6 staging fragments per wave: ids 0..7 = A (rtl=id>>2, c=id&3),
    // ids 8..23 = B (kc=(id-8)>>2, cg=(id-8)&3)
    const unsigned short* gp[6];
    const unsigned short* lp[6];
    int ginc[6], linc[6];
    #pragma unroll
    for (int j = 0; j < 6; j++) {
        const int id = w * 6 + j;
        if (id < 8) {
            const int art = id >> 2, c = id & 3;
            gp[j] = K0 + (((size_t)(b * 256 + rt0 + art)) * 128 + c) * 512 + lane * 8;
            lp[j] = As + id * 512;
            ginc[j] = 4 * 512;      // advance 4 k32-chunks
            linc[j] = 8 * 512;      // buf1 offset
        } else {
            const int bi = id - 8, kc = bi >> 2, cg = bi & 3;
            gp[j] = xdT + (((size_t)(b * 128 + kc)) * 4 + cg) * 512 + lane * 8;
            lp[j] = Bs + bi * 512;
            ginc[j] = 4 * 2048;     // 4 k32-chunks * 2048 shorts
            linc[j] = 16 * 512;
        }
    }

    asm volatile("s_waitcnt vmcnt(0)" ::: "memory"); // dsc/wsc retired
    __builtin_amdgcn_sched_barrier(0);

    // prologue: stage buffer 0 (k32 = 0..3)
    #pragma unroll
    for (int j = 0; j < 6; j++) {
        gll16(gp[j], lp[j]);
        gp[j] += ginc[j];
    }

    f32x4 acc0 = {0.f,0.f,0.f,0.f}, acc1 = {0.f,0.f,0.f,0.f};
    const int lo = lane * 8;
    int cur = 0;

    for (int t4 = 0; t4 < 32; t4++) {
        if (t4 < 31) {
            // stage next buffer (into cur^1)
            #pragma unroll
            for (int j = 0; j < 6; j++) {
                gll16(gp[j], lp[j] + (cur ? 0 : linc[j]));
                gp[j] += ginc[j];
            }
        }
        __builtin_amdgcn_sched_barrier(0);
        if (t4 < 31) asm volatile("s_waitcnt vmcnt(6)" ::: "memory"); // my cur chunks done
        else         asm volatile("s_waitcnt vmcnt(0)" ::: "memory"); // tail: drain
        __builtin_amdgcn_s_barrier();           // everyone's cur chunks done
        __builtin_amdgcn_sched_barrier(0);

        const unsigned short* Ab = As + (cur ? 8 * 512 : 0) + rtl * 4 * 512 + lo;
        const unsigned short* Bb = Bs + (cur ? 16 * 512 : 0) + cgp * 512 + lo;
        #pragma unroll
        for (int c = 0; c < 4; c++) {
            bf16x8 av = *(const bf16x8*)(Ab + c * 512);
            bf16x8 b0 = *(const bf16x8*)(Bb + c * 2048);
            bf16x8 b1 = *(const bf16x8*)(Bb + c * 2048 + 512);
            acc0 = __builtin_amdgcn_mfma_f32_16x16x32_bf16(av, b0, acc0, 0, 0, 0);
            acc1 = __builtin_amdgcn_mfma_f32_16x16x32_bf16(av, b1, acc1, 0, 0, 0);
        }
        __builtin_amdgcn_sched_barrier(0);
        __builtin_amdgcn_s_barrier();           // cur reads done before overwrite
        cur ^= 1;
    }

    // epilogue: pre-scaled direct stores (each output element written once)
    #pragma unroll
    for (int r = 0; r < 4; r++) {
        const int row = rt * 16 + fq * 4 + r;
        float* op = out + ((size_t)(b * N_ + row)) * C_;
        op[cgp * 16 + fr]      = dsc[r] * acc0[r];
        op[cgp * 16 + 16 + fr] = dsc[r] * acc1[r];
    }
}

extern "C" void kernel_launch(void* const* d_in, const int* in_sizes, int n_in,
                              void* d_out, int out_size, void* d_ws, size_t ws_size,
                              hipStream_t stream)
{
    const float* x   = (const float*)d_in[0];
    const float* W   = (const float*)d_in[1];
    const float* U   = (const float*)d_in[2];
    const float* wsc = (const float*)d_in[3];
    float* out = (float*)d_out;

    // workspace: K0f (bf16, 128 MiB) | deg (fp32, 64 KiB) | xdTf (bf16, 2 MiB)
    unsigned short* K0  = (unsigned short*)d_ws;
    float*          deg = (float*)((char*)d_ws + (size_t)B_ * N_ * N_ * 2);
    unsigned short* xdT = (unsigned short*)((char*)deg + (size_t)B_ * N_ * 4);

    hipMemsetAsync(deg, 0, (size_t)B_ * N_ * sizeof(float), stream);
    hipLaunchKernelGGL(k_pass1, dim3(64, 64), dim3(256), 0, stream, W, U, K0, deg);
    hipLaunchKernelGGL(k_xdT,  dim3(64, 4),   dim3(256), 0, stream, x, deg, xdT);
    hipLaunchKernelGGL(k_gemm, dim3(128, 4),  dim3(256), 0, stream, K0, xdT, deg, wsc, out);
}

// Round 2
// 434.391 us; speedup vs baseline: 1.0495x; 1.0239x over previous
//
#include <hip/hip_runtime.h>
#include <hip/hip_bf16.h>

#define B_ 4
#define N_ 4096
#define C_ 64
#define R_ 16
#define EPS_ 1e-12f

typedef __attribute__((ext_vector_type(8))) short bf16x8;
typedef __attribute__((ext_vector_type(4))) float f32x4;

static __device__ __forceinline__ unsigned short f2bf(float f) {
    unsigned int u = __float_as_uint(f);
    unsigned int r = (u + 0x7fffu + ((u >> 16) & 1u)) >> 16;
    return (unsigned short)r;
}
static __device__ __forceinline__ float bf2f(unsigned short us) {
    return __uint_as_float(((unsigned int)us) << 16);
}

// K0f fragment layout: [b][rowtile=row/16][k32=k/32][fq=(k/8)&3][fr=row&15][e=k&7]
static __device__ __forceinline__ size_t k0f_off(int b, int rt, int k32, int fq, int fr) {
    return ((((size_t)(b * 256 + rt)) * 128 + k32) * 4 + fq) * 128 + fr * 8;
}

// Pass 1 (v2): triangular grid (2080 blocks), ONE barrier per batch via
// double-buffered LDS: Wc packed bf16 [2][64][66], K0s [2][64][72].
// LDS = 4.35 + 16.9 + 18.4 = 39.6 KB -> 4 blocks/CU (VGPR-bound anyway).
__global__ __launch_bounds__(256) void k_pass1(
    const float* __restrict__ W, const float* __restrict__ U,
    unsigned short* __restrict__ K0, float* __restrict__ deg)
{
    // decode lin -> (ti,tj), ti<=tj, base(t)=t*(129-t)/2
    const int lin = blockIdx.x;
    float ff = 64.5f - sqrtf(64.5f * 64.5f - 2.0f * (float)lin);
    int ti = (int)ff;
    while ((ti + 1) * (129 - (ti + 1)) / 2 <= lin) ti++;
    while (ti * (129 - ti) / 2 > lin) ti--;
    const int tj = ti + (lin - ti * (129 - ti) / 2);
    const int I = ti * 64, J = tj * 64;
    const bool diag = (ti == tj);
    const int t = threadIdx.x;
    const int ii = t >> 2, g = t & 3, jjg = g * 16;

    __shared__ float UJ[64][17];
    __shared__ unsigned short Wc[2][64][66];          // bf16 W-column tile, dbuf
    __shared__ __align__(16) unsigned short K0s[2][64][72]; // bf16 K tile, dbuf

    {
        const float4 v = *(const float4*)(U + (size_t)(J + (t >> 2)) * R_ + (t & 3) * 4);
        UJ[t >> 2][(t & 3) * 4 + 0] = v.x;
        UJ[t >> 2][(t & 3) * 4 + 1] = v.y;
        UJ[t >> 2][(t & 3) * 4 + 2] = v.z;
        UJ[t >> 2][(t & 3) * 4 + 3] = v.w;
    }

    float4 wcv[4], wrv[4], wcvN[4], wrvN[4];
    #pragma unroll
    for (int k = 0; k < 4; k++) {
        const int idx = t + 256 * k, row = idx >> 4, c4 = idx & 15;
        wcv[k] = *(const float4*)(W + ((size_t)(0 * N_ + J + row)) * N_ + I + c4 * 4);
    }
    #pragma unroll
    for (int h = 0; h < 4; h++)
        wrv[h] = *(const float4*)(W + ((size_t)(0 * N_ + I + ii)) * N_ + J + jjg + 4 * h);

    float ui[16];
    {
        const float* up = U + (size_t)(I + ii) * R_;
        #pragma unroll
        for (int h = 0; h < 4; h++) {
            float4 v = *(const float4*)(up + 4 * h);
            ui[4*h] = v.x; ui[4*h+1] = v.y; ui[4*h+2] = v.z; ui[4*h+3] = v.w;
        }
    }
    __syncthreads(); // UJ ready

    // a[] compute overlaps the wcv/wrv load latency
    float a[16];
    #pragma unroll
    for (int q = 0; q < 16; q++) {
        float s = 0.f;
        #pragma unroll
        for (int k = 0; k < 16; k++) s += ui[k] * UJ[jjg + q][k];
        a[q] = 1.0f / (1.0f + __expf(-s));
    }

    // pack b=0 column tile into Wc[0]
    #pragma unroll
    for (int k = 0; k < 4; k++) {
        const int idx = t + 256 * k, row = idx >> 4, c4 = idx & 15;
        unsigned int d0 = (unsigned int)f2bf(wcv[k].x) | ((unsigned int)f2bf(wcv[k].y) << 16);
        unsigned int d1 = (unsigned int)f2bf(wcv[k].z) | ((unsigned int)f2bf(wcv[k].w) << 16);
        *(unsigned int*)&Wc[0][row][c4 * 4]     = d0;
        *(unsigned int*)&Wc[0][row][c4 * 4 + 2] = d1;
    }
    __syncthreads(); // Wc[0] ready

    for (int b = 0; b < B_; b++) {
        const int cur = b & 1;
        if (b < B_ - 1) {
            #pragma unroll
            for (int k = 0; k < 4; k++) {
                const int idx = t + 256 * k, row = idx >> 4, c4 = idx & 15;
                wcvN[k] = *(const float4*)(W + ((size_t)((b+1) * N_ + J + row)) * N_ + I + c4 * 4);
            }
            #pragma unroll
            for (int h = 0; h < 4; h++)
                wrvN[h] = *(const float4*)(W + ((size_t)((b+1) * N_ + I + ii)) * N_ + J + jjg + 4 * h);
        }

        const float* wrf = (const float*)wrv;
        float sumI = 0.f;
        unsigned int pk[8];
        #pragma unroll
        for (int q = 0; q < 16; q++) {
            float k0 = 0.5f * (wrf[q] + bf2f(Wc[cur][jjg + q][ii])) * a[q];
            sumI += k0;
            unsigned short us = f2bf(k0);
            if (q & 1) pk[q >> 1] |= ((unsigned int)us) << 16;
            else       pk[q >> 1] = us;
        }
        *(int4*)(&K0s[cur][ii][jjg])     = make_int4(pk[0], pk[1], pk[2], pk[3]);
        *(int4*)(&K0s[cur][ii][jjg + 8]) = make_int4(pk[4], pk[5], pk[6], pk[7]);
        // row-orientation fragment store: row I+ii, k = J+g*16 .. +15
        {
            const int rt  = (I + ii) >> 4, fr = ii & 15;
            const int k32 = (J >> 5) + (g >> 1), fqa = (g & 1) * 2;
            unsigned short* dst = K0 + k0f_off(b, rt, k32, fqa, fr);
            *(int4*)(dst)       = make_int4(pk[0], pk[1], pk[2], pk[3]);
            *(int4*)(dst + 128) = make_int4(pk[4], pk[5], pk[6], pk[7]);
        }
        {
            float s = sumI + __shfl_xor(sumI, 1, 64);
            s += __shfl_xor(s, 2, 64);
            if (g == 0) atomicAdd(deg + b * N_ + I + ii, s);
        }
        if (b < B_ - 1) {
            // write the OTHER Wc buffer (no readers until after the barrier)
            #pragma unroll
            for (int k = 0; k < 4; k++) {
                const int idx = t + 256 * k, row = idx >> 4, c4 = idx & 15;
                unsigned int d0 = (unsigned int)f2bf(wcvN[k].x) | ((unsigned int)f2bf(wcvN[k].y) << 16);
                unsigned int d1 = (unsigned int)f2bf(wcvN[k].z) | ((unsigned int)f2bf(wcvN[k].w) << 16);
                *(unsigned int*)&Wc[cur ^ 1][row][c4 * 4]     = d0;
                *(unsigned int*)&Wc[cur ^ 1][row][c4 * 4 + 2] = d1;
            }
            #pragma unroll
            for (int h = 0; h < 4; h++) wrv[h] = wrvN[h];
        }
        __syncthreads(); // K0s[cur] + Wc[cur^1] visible; all Wc[cur]/K0s[cur^1] uses done

        if (!diag) {
            const int c2 = t & 31, r8 = t >> 5; // cols j=2c2,2c2+1; rows i=r8*8..+7
            unsigned int v[8];
            float cs0 = 0.f, cs1 = 0.f;
            #pragma unroll
            for (int k = 0; k < 8; k++) {
                v[k] = *(const unsigned int*)(&K0s[cur][r8 * 8 + k][c2 * 2]);
                cs0 += bf2f((unsigned short)(v[k] & 0xffffu));
                cs1 += bf2f((unsigned short)(v[k] >> 16));
            }
            unsigned int plo[4], phi[4];
            #pragma unroll
            for (int m = 0; m < 4; m++) {
                plo[m] = (v[2*m] & 0xffffu) | (v[2*m+1] << 16);
                phi[m] = (v[2*m] >> 16) | (v[2*m+1] & 0xffff0000u);
            }
            // transposed fragment store: out row J+2c2(+1), k = I+r8*8 .. +7
            const int rtp  = (J >> 4) + (c2 >> 3), fr0 = (2 * c2) & 15;
            const int k32p = (I >> 5) + (r8 >> 2), fqp = r8 & 3;
            unsigned short* dst0 = K0 + k0f_off(b, rtp, k32p, fqp, fr0);
            *(int4*)(dst0)     = make_int4(plo[0], plo[1], plo[2], plo[3]);
            *(int4*)(dst0 + 8) = make_int4(phi[0], phi[1], phi[2], phi[3]);
            cs0 += __shfl_xor(cs0, 32, 64);
            cs1 += __shfl_xor(cs1, 32, 64);
            if ((t & 32) == 0) {
                atomicAdd(deg + b * N_ + J + 2 * c2,     cs0);
                atomicAdd(deg + b * N_ + J + 2 * c2 + 1, cs1);
            }
        }
    }
}

// xdTf fragment layout: [b][k32=j/32][cg=c/16][fq=(j/8)&3][fr=c&15][e=j&7]
// value = bf16( x[b,j,c] * rsqrt(deg[b,j]) )
__global__ __launch_bounds__(256) void k_xdT(
    const float* __restrict__ x, const float* __restrict__ deg,
    unsigned short* __restrict__ xdT)
{
    const int jt = blockIdx.x, b = blockIdx.y;
    const int J = jt * 64, t = threadIdx.x;
    __shared__ float xt[64][69];
    #pragma unroll
    for (int k = 0; k < 4; k++) {
        int idx = t + 256 * k;
        int row = idx >> 4, f4 = idx & 15;
        float d = rsqrtf(fmaxf(deg[b * N_ + J + row], EPS_));
        float4 v = *(const float4*)(x + ((size_t)(b * N_ + J + row)) * C_ + f4 * 4);
        xt[row][f4*4+0] = v.x * d; xt[row][f4*4+1] = v.y * d;
        xt[row][f4*4+2] = v.z * d; xt[row][f4*4+3] = v.w * d;
    }
    __syncthreads();
    #pragma unroll
    for (int p = 0; p < 2; p++) {
        const int linear = p * 256 + t;
        const int k32h = linear >> 8, rem = linear & 255;
        const int cg = rem >> 6, l = rem & 63, fq = l >> 4, fr = l & 15;
        const int c = cg * 16 + fr;
        const int jb = k32h * 32 + fq * 8;
        unsigned int pk[4];
        #pragma unroll
        for (int m = 0; m < 4; m++) {
            pk[m] = (unsigned int)f2bf(xt[jb + 2*m][c]) |
                    ((unsigned int)f2bf(xt[jb + 2*m + 1][c]) << 16);
        }
        unsigned short* dst = xdT +
            (((size_t)(b * 128 + (J >> 5) + k32h)) * 4 + cg) * 512 + l * 8;
        *(int4*)dst = make_int4(pk[0], pk[1], pk[2], pk[3]);
    }
}

// Async 16B global->LDS. LDS dest is wave-uniform base; HW appends lane*16.
static __device__ __forceinline__ void gll16(const unsigned short* g, const unsigned short* l) {
    __builtin_amdgcn_global_load_lds(
        (const __attribute__((address_space(1))) unsigned int*)g,
        (__attribute__((address_space(3))) unsigned int*)l,
        16, 0, 0);
}

// Pass 2: cooperative 256-thread block, M=32 x N=64, full K=4096.
// Double-buffered global_load_lds pipeline, counted vmcnt(6), raw s_barrier.
__global__ __launch_bounds__(256, 2) void k_gemm(
    const unsigned short* __restrict__ K0, const unsigned short* __restrict__ xdT,
    const float* __restrict__ deg, const float* __restrict__ wsc_p,
    float* __restrict__ out)
{
    const int mg = blockIdx.x, b = blockIdx.y;
    const int t = threadIdx.x, w = t >> 6, lane = t & 63;
    const int rt0 = mg * 2;
    const int rtl = w & 1, cgp = (w >> 1) * 2;
    const int fq = lane >> 4, fr = lane & 15;
    const int rt = rt0 + rtl;

    __shared__ __align__(16) unsigned short As[2 * 8 * 512];   // [buf][rtl*4+c][512]
    __shared__ __align__(16) unsigned short Bs[2 * 16 * 512];  // [buf][c*4+cg][512]

    const float wsc = wsc_p[0];
    float dsc[4];
    #pragma unroll
    for (int r = 0; r < 4; r++)
        dsc[r] = wsc * rsqrtf(fmaxf(deg[b * N_ + rt * 16 + fq * 4 + r], EPS_));

    const unsigned short* gp[6];
    const unsigned short* lp[6];
    int ginc[6], linc[6];
    #pragma unroll
    for (int j = 0; j < 6; j++) {
        const int id = w * 6 + j;
        if (id < 8) {
            const int art = id >> 2, c = id & 3;
            gp[j] = K0 + (((size_t)(b * 256 + rt0 + art)) * 128 + c) * 512 + lane * 8;
            lp[j] = As + id * 512;
            ginc[j] = 4 * 512;
            linc[j] = 8 * 512;
        } else {
            const int bi = id - 8, kc = bi >> 2, cg = bi & 3;
            gp[j] = xdT + (((size_t)(b * 128 + kc)) * 4 + cg) * 512 + lane * 8;
            lp[j] = Bs + bi * 512;
            ginc[j] = 4 * 2048;
            linc[j] = 16 * 512;
        }
    }

    asm volatile("s_waitcnt vmcnt(0)" ::: "memory"); // dsc/wsc retired
    __builtin_amdgcn_sched_barrier(0);

    #pragma unroll
    for (int j = 0; j < 6; j++) {
        gll16(gp[j], lp[j]);
        gp[j] += ginc[j];
    }

    f32x4 acc0 = {0.f,0.f,0.f,0.f}, acc1 = {0.f,0.f,0.f,0.f};
    const int lo = lane * 8;
    int cur = 0;

    for (int t4 = 0; t4 < 32; t4++) {
        if (t4 < 31) {
            #pragma unroll
            for (int j = 0; j < 6; j++) {
                gll16(gp[j], lp[j] + (cur ? 0 : linc[j]));
                gp[j] += ginc[j];
            }
        }
        __builtin_amdgcn_sched_barrier(0);
        if (t4 < 31) asm volatile("s_waitcnt vmcnt(6)" ::: "memory");
        else         asm volatile("s_waitcnt vmcnt(0)" ::: "memory");
        __builtin_amdgcn_s_barrier();
        __builtin_amdgcn_sched_barrier(0);

        const unsigned short* Ab = As + (cur ? 8 * 512 : 0) + rtl * 4 * 512 + lo;
        const unsigned short* Bb = Bs + (cur ? 16 * 512 : 0) + cgp * 512 + lo;
        #pragma unroll
        for (int c = 0; c < 4; c++) {
            bf16x8 av = *(const bf16x8*)(Ab + c * 512);
            bf16x8 b0 = *(const bf16x8*)(Bb + c * 2048);
            bf16x8 b1 = *(const bf16x8*)(Bb + c * 2048 + 512);
            acc0 = __builtin_amdgcn_mfma_f32_16x16x32_bf16(av, b0, acc0, 0, 0, 0);
            acc1 = __builtin_amdgcn_mfma_f32_16x16x32_bf16(av, b1, acc1, 0, 0, 0);
        }
        __builtin_amdgcn_sched_barrier(0);
        __builtin_amdgcn_s_barrier();
        cur ^= 1;
    }

    #pragma unroll
    for (int r = 0; r < 4; r++) {
        const int row = rt * 16 + fq * 4 + r;
        float* op = out + ((size_t)(b * N_ + row)) * C_;
        op[cgp * 16 + fr]      = dsc[r] * acc0[r];
        op[cgp * 16 + 16 + fr] = dsc[r] * acc1[r];
    }
}

extern "C" void kernel_launch(void* const* d_in, const int* in_sizes, int n_in,
                              void* d_out, int out_size, void* d_ws, size_t ws_size,
                              hipStream_t stream)
{
    const float* x   = (const float*)d_in[0];
    const float* W   = (const float*)d_in[1];
    const float* U   = (const float*)d_in[2];
    const float* wsc = (const float*)d_in[3];
    float* out = (float*)d_out;

    // workspace: K0f (bf16, 128 MiB) | deg (fp32, 64 KiB) | xdTf (bf16, 2 MiB)
    unsigned short* K0  = (unsigned short*)d_ws;
    float*          deg = (float*)((char*)d_ws + (size_t)B_ * N_ * N_ * 2);
    unsigned short* xdT = (unsigned short*)((char*)deg + (size_t)B_ * N_ * 4);

    hipMemsetAsync(deg, 0, (size_t)B_ * N_ * sizeof(float), stream);
    hipLaunchKernelGGL(k_pass1, dim3(2080), dim3(256), 0, stream, W, U, K0, deg);
    hipLaunchKernelGGL(k_xdT,  dim3(64, 4),   dim3(256), 0, stream, x, deg, xdT);
    hipLaunchKernelGGL(k_gemm, dim3(128, 4),  dim3(256), 0, stream, K0, xdT, deg, wsc, out);
}

// Round 3
// 431.332 us; speedup vs baseline: 1.0569x; 1.0071x over previous
//
#include <hip/hip_runtime.h>
#include <hip/hip_bf16.h>

#define B_ 4
#define N_ 4096
#define C_ 64
#define R_ 16
#define EPS_ 1e-12f

typedef __attribute__((ext_vector_type(8))) short bf16x8;
typedef __attribute__((ext_vector_type(4))) float f32x4;

static __device__ __forceinline__ unsigned short f2bf(float f) {
    unsigned int u = __float_as_uint(f);
    unsigned int r = (u + 0x7fffu + ((u >> 16) & 1u)) >> 16;
    return (unsigned short)r;
}
static __device__ __forceinline__ float bf2f(unsigned short us) {
    return __uint_as_float(((unsigned int)us) << 16);
}

// K0f fragment layout: [b][rowtile=row/16][k32=k/32][fq=(k/8)&3][fr=row&15][e=k&7]
static __device__ __forceinline__ size_t k0f_off(int b, int rt, int k32, int fq, int fr) {
    return ((((size_t)(b * 256 + rt)) * 128 + k32) * 4 + fq) * 128 + fr * 8;
}

// Pass 1: triangular grid (2080 blocks), ONE barrier per batch via
// double-buffered LDS: Wc packed bf16 [2][64][66], K0s [2][64][72].
__global__ __launch_bounds__(256) void k_pass1(
    const float* __restrict__ W, const float* __restrict__ U,
    unsigned short* __restrict__ K0, float* __restrict__ deg)
{
    // decode lin -> (ti,tj), ti<=tj, base(t)=t*(129-t)/2
    const int lin = blockIdx.x;
    float ff = 64.5f - sqrtf(64.5f * 64.5f - 2.0f * (float)lin);
    int ti = (int)ff;
    while ((ti + 1) * (129 - (ti + 1)) / 2 <= lin) ti++;
    while (ti * (129 - ti) / 2 > lin) ti--;
    const int tj = ti + (lin - ti * (129 - ti) / 2);
    const int I = ti * 64, J = tj * 64;
    const bool diag = (ti == tj);
    const int t = threadIdx.x;
    const int ii = t >> 2, g = t & 3, jjg = g * 16;

    __shared__ float UJ[64][17];
    __shared__ unsigned short Wc[2][64][66];          // bf16 W-column tile, dbuf
    __shared__ __align__(16) unsigned short K0s[2][64][72]; // bf16 K tile, dbuf

    {
        const float4 v = *(const float4*)(U + (size_t)(J + (t >> 2)) * R_ + (t & 3) * 4);
        UJ[t >> 2][(t & 3) * 4 + 0] = v.x;
        UJ[t >> 2][(t & 3) * 4 + 1] = v.y;
        UJ[t >> 2][(t & 3) * 4 + 2] = v.z;
        UJ[t >> 2][(t & 3) * 4 + 3] = v.w;
    }

    float4 wcv[4], wrv[4], wcvN[4], wrvN[4];
    #pragma unroll
    for (int k = 0; k < 4; k++) {
        const int idx = t + 256 * k, row = idx >> 4, c4 = idx & 15;
        wcv[k] = *(const float4*)(W + ((size_t)(0 * N_ + J + row)) * N_ + I + c4 * 4);
    }
    #pragma unroll
    for (int h = 0; h < 4; h++)
        wrv[h] = *(const float4*)(W + ((size_t)(0 * N_ + I + ii)) * N_ + J + jjg + 4 * h);

    float ui[16];
    {
        const float* up = U + (size_t)(I + ii) * R_;
        #pragma unroll
        for (int h = 0; h < 4; h++) {
            float4 v = *(const float4*)(up + 4 * h);
            ui[4*h] = v.x; ui[4*h+1] = v.y; ui[4*h+2] = v.z; ui[4*h+3] = v.w;
        }
    }
    __syncthreads(); // UJ ready

    float a[16];
    #pragma unroll
    for (int q = 0; q < 16; q++) {
        float s = 0.f;
        #pragma unroll
        for (int k = 0; k < 16; k++) s += ui[k] * UJ[jjg + q][k];
        a[q] = 1.0f / (1.0f + __expf(-s));
    }

    // pack b=0 column tile into Wc[0]
    #pragma unroll
    for (int k = 0; k < 4; k++) {
        const int idx = t + 256 * k, row = idx >> 4, c4 = idx & 15;
        unsigned int d0 = (unsigned int)f2bf(wcv[k].x) | ((unsigned int)f2bf(wcv[k].y) << 16);
        unsigned int d1 = (unsigned int)f2bf(wcv[k].z) | ((unsigned int)f2bf(wcv[k].w) << 16);
        *(unsigned int*)&Wc[0][row][c4 * 4]     = d0;
        *(unsigned int*)&Wc[0][row][c4 * 4 + 2] = d1;
    }
    __syncthreads(); // Wc[0] ready

    for (int b = 0; b < B_; b++) {
        const int cur = b & 1;
        if (b < B_ - 1) {
            #pragma unroll
            for (int k = 0; k < 4; k++) {
                const int idx = t + 256 * k, row = idx >> 4, c4 = idx & 15;
                wcvN[k] = *(const float4*)(W + ((size_t)((b+1) * N_ + J + row)) * N_ + I + c4 * 4);
            }
            #pragma unroll
            for (int h = 0; h < 4; h++)
                wrvN[h] = *(const float4*)(W + ((size_t)((b+1) * N_ + I + ii)) * N_ + J + jjg + 4 * h);
        }

        const float* wrf = (const float*)wrv;
        float sumI = 0.f;
        unsigned int pk[8];
        #pragma unroll
        for (int q = 0; q < 16; q++) {
            float k0 = 0.5f * (wrf[q] + bf2f(Wc[cur][jjg + q][ii])) * a[q];
            sumI += k0;
            unsigned short us = f2bf(k0);
            if (q & 1) pk[q >> 1] |= ((unsigned int)us) << 16;
            else       pk[q >> 1] = us;
        }
        *(int4*)(&K0s[cur][ii][jjg])     = make_int4(pk[0], pk[1], pk[2], pk[3]);
        *(int4*)(&K0s[cur][ii][jjg + 8]) = make_int4(pk[4], pk[5], pk[6], pk[7]);
        // row-orientation fragment store: row I+ii, k = J+g*16 .. +15
        {
            const int rt  = (I + ii) >> 4, fr = ii & 15;
            const int k32 = (J >> 5) + (g >> 1), fqa = (g & 1) * 2;
            unsigned short* dst = K0 + k0f_off(b, rt, k32, fqa, fr);
            *(int4*)(dst)       = make_int4(pk[0], pk[1], pk[2], pk[3]);
            *(int4*)(dst + 128) = make_int4(pk[4], pk[5], pk[6], pk[7]);
        }
        {
            float s = sumI + __shfl_xor(sumI, 1, 64);
            s += __shfl_xor(s, 2, 64);
            if (g == 0) atomicAdd(deg + b * N_ + I + ii, s);
        }
        if (b < B_ - 1) {
            // write the OTHER Wc buffer (no readers until after the barrier)
            #pragma unroll
            for (int k = 0; k < 4; k++) {
                const int idx = t + 256 * k, row = idx >> 4, c4 = idx & 15;
                unsigned int d0 = (unsigned int)f2bf(wcvN[k].x) | ((unsigned int)f2bf(wcvN[k].y) << 16);
                unsigned int d1 = (unsigned int)f2bf(wcvN[k].z) | ((unsigned int)f2bf(wcvN[k].w) << 16);
                *(unsigned int*)&Wc[cur ^ 1][row][c4 * 4]     = d0;
                *(unsigned int*)&Wc[cur ^ 1][row][c4 * 4 + 2] = d1;
            }
            #pragma unroll
            for (int h = 0; h < 4; h++) wrv[h] = wrvN[h];
        }
        __syncthreads(); // K0s[cur] + Wc[cur^1] visible; all Wc[cur]/K0s[cur^1] uses done

        if (!diag) {
            const int c2 = t & 31, r8 = t >> 5; // cols j=2c2,2c2+1; rows i=r8*8..+7
            unsigned int v[8];
            float cs0 = 0.f, cs1 = 0.f;
            #pragma unroll
            for (int k = 0; k < 8; k++) {
                v[k] = *(const unsigned int*)(&K0s[cur][r8 * 8 + k][c2 * 2]);
                cs0 += bf2f((unsigned short)(v[k] & 0xffffu));
                cs1 += bf2f((unsigned short)(v[k] >> 16));
            }
            unsigned int plo[4], phi[4];
            #pragma unroll
            for (int m = 0; m < 4; m++) {
                plo[m] = (v[2*m] & 0xffffu) | (v[2*m+1] << 16);
                phi[m] = (v[2*m] >> 16) | (v[2*m+1] & 0xffff0000u);
            }
            // transposed fragment store: out row J+2c2(+1), k = I+r8*8 .. +7
            const int rtp  = (J >> 4) + (c2 >> 3), fr0 = (2 * c2) & 15;
            const int k32p = (I >> 5) + (r8 >> 2), fqp = r8 & 3;
            unsigned short* dst0 = K0 + k0f_off(b, rtp, k32p, fqp, fr0);
            *(int4*)(dst0)     = make_int4(plo[0], plo[1], plo[2], plo[3]);
            *(int4*)(dst0 + 8) = make_int4(phi[0], phi[1], phi[2], phi[3]);
            cs0 += __shfl_xor(cs0, 32, 64);
            cs1 += __shfl_xor(cs1, 32, 64);
            if ((t & 32) == 0) {
                atomicAdd(deg + b * N_ + J + 2 * c2,     cs0);
                atomicAdd(deg + b * N_ + J + 2 * c2 + 1, cs1);
            }
        }
    }
}

// xdTf fragment layout: [b][k32=j/32][cg=c/16][fq=(j/8)&3][fr=c&15][e=j&7]
// value = bf16( x[b,j,c] * rsqrt(deg[b,j]) )
__global__ __launch_bounds__(256) void k_xdT(
    const float* __restrict__ x, const float* __restrict__ deg,
    unsigned short* __restrict__ xdT)
{
    const int jt = blockIdx.x, b = blockIdx.y;
    const int J = jt * 64, t = threadIdx.x;
    __shared__ float xt[64][69];
    #pragma unroll
    for (int k = 0; k < 4; k++) {
        int idx = t + 256 * k;
        int row = idx >> 4, f4 = idx & 15;
        float d = rsqrtf(fmaxf(deg[b * N_ + J + row], EPS_));
        float4 v = *(const float4*)(x + ((size_t)(b * N_ + J + row)) * C_ + f4 * 4);
        xt[row][f4*4+0] = v.x * d; xt[row][f4*4+1] = v.y * d;
        xt[row][f4*4+2] = v.z * d; xt[row][f4*4+3] = v.w * d;
    }
    __syncthreads();
    #pragma unroll
    for (int p = 0; p < 2; p++) {
        const int linear = p * 256 + t;
        const int k32h = linear >> 8, rem = linear & 255;
        const int cg = rem >> 6, l = rem & 63, fq = l >> 4, fr = l & 15;
        const int c = cg * 16 + fr;
        const int jb = k32h * 32 + fq * 8;
        unsigned int pk[4];
        #pragma unroll
        for (int m = 0; m < 4; m++) {
            pk[m] = (unsigned int)f2bf(xt[jb + 2*m][c]) |
                    ((unsigned int)f2bf(xt[jb + 2*m + 1][c]) << 16);
        }
        unsigned short* dst = xdT +
            (((size_t)(b * 128 + (J >> 5) + k32h)) * 4 + cg) * 512 + l * 8;
        *(int4*)dst = make_int4(pk[0], pk[1], pk[2], pk[3]);
    }
}

// Async 16B global->LDS. LDS dest is wave-uniform base; HW appends lane*16.
static __device__ __forceinline__ void gll16(const unsigned short* g, const unsigned short* l) {
    __builtin_amdgcn_global_load_lds(
        (const __attribute__((address_space(1))) unsigned int*)g,
        (__attribute__((address_space(3))) unsigned int*)l,
        16, 0, 0);
}

// Pass 2 (v3): cooperative 256-thread block, M=32 x N=64, full K=4096.
// TRIPLE-buffered global_load_lds pipeline, 2-deep prefetch, ONE barrier per
// K-step. Stage is issued AFTER the barrier so the barrier is the WAR fence:
// every wave's ds_reads of the overwrite target were consumed by MFMAs
// (lgkm-forced) before that wave reached the barrier. vmcnt(6) steady.
// LDS 72 KB -> 2 blocks/CU (144 KB).
__global__ __launch_bounds__(256, 2) void k_gemm(
    const unsigned short* __restrict__ K0, const unsigned short* __restrict__ xdT,
    const float* __restrict__ deg, const float* __restrict__ wsc_p,
    float* __restrict__ out)
{
    const int mg = blockIdx.x, b = blockIdx.y;
    const int t = threadIdx.x, w = t >> 6, lane = t & 63;
    const int rt0 = mg * 2;
    const int rtl = w & 1, cgp = (w >> 1) * 2;
    const int fq = lane >> 4, fr = lane & 15;
    const int rt = rt0 + rtl;

    __shared__ __align__(16) unsigned short As[3 * 8 * 512];   // [slot][rtl*4+c][512]
    __shared__ __align__(16) unsigned short Bs[3 * 16 * 512];  // [slot][c*4+cg][512]

    const float wsc = wsc_p[0];
    float dsc[4];
    #pragma unroll
    for (int r = 0; r < 4; r++)
        dsc[r] = wsc * rsqrtf(fmaxf(deg[b * N_ + rt * 16 + fq * 4 + r], EPS_));

    // 6 staging fragments per wave: ids 0..7 = A, ids 8..23 = B
    const unsigned short* gp[6];
    const unsigned short* lp[6];
    int ginc[6], linc[6];
    #pragma unroll
    for (int j = 0; j < 6; j++) {
        const int id = w * 6 + j;
        if (id < 8) {
            const int art = id >> 2, c = id & 3;
            gp[j] = K0 + (((size_t)(b * 256 + rt0 + art)) * 128 + c) * 512 + lane * 8;
            lp[j] = As + id * 512;
            ginc[j] = 4 * 512;      // advance 4 k32-chunks
            linc[j] = 8 * 512;      // slot stride (A)
        } else {
            const int bi = id - 8, kc = bi >> 2, cg = bi & 3;
            gp[j] = xdT + (((size_t)(b * 128 + kc)) * 4 + cg) * 512 + lane * 8;
            lp[j] = Bs + bi * 512;
            ginc[j] = 4 * 2048;     // 4 k32-chunks * 2048 shorts
            linc[j] = 16 * 512;     // slot stride (B)
        }
    }

    asm volatile("s_waitcnt vmcnt(0)" ::: "memory"); // dsc/wsc retired
    __builtin_amdgcn_sched_barrier(0);

    // prologue: stage slots 0 (t4=0) and 1 (t4=1)
    #pragma unroll
    for (int j = 0; j < 6; j++) { gll16(gp[j], lp[j]);            gp[j] += ginc[j]; }
    #pragma unroll
    for (int j = 0; j < 6; j++) { gll16(gp[j], lp[j] + linc[j]);  gp[j] += ginc[j]; }

    f32x4 acc0 = {0.f,0.f,0.f,0.f}, acc1 = {0.f,0.f,0.f,0.f};
    const int lo = lane * 8;
    int slot = 0;

    for (int t4 = 0; t4 < 32; t4++) {
        if (t4 < 31) asm volatile("s_waitcnt vmcnt(6)" ::: "memory"); // my slot-t4 chunks done
        else         asm volatile("s_waitcnt vmcnt(0)" ::: "memory"); // tail: drain
        __builtin_amdgcn_s_barrier();           // everyone's slot-t4 chunks visible; WAR fence
        __builtin_amdgcn_sched_barrier(0);

        if (t4 < 30) {
            const int s2 = (slot >= 1) ? slot - 1 : slot + 2;  // (slot+2) % 3
            #pragma unroll
            for (int j = 0; j < 6; j++) {
                gll16(gp[j], lp[j] + s2 * linc[j]);
                gp[j] += ginc[j];
            }
        }
        __builtin_amdgcn_sched_barrier(0);

        const unsigned short* Ab = As + slot * (8 * 512)  + rtl * 4 * 512 + lo;
        const unsigned short* Bb = Bs + slot * (16 * 512) + cgp * 512 + lo;
        #pragma unroll
        for (int c = 0; c < 4; c++) {
            bf16x8 av = *(const bf16x8*)(Ab + c * 512);
            bf16x8 b0 = *(const bf16x8*)(Bb + c * 2048);
            bf16x8 b1 = *(const bf16x8*)(Bb + c * 2048 + 512);
            acc0 = __builtin_amdgcn_mfma_f32_16x16x32_bf16(av, b0, acc0, 0, 0, 0);
            acc1 = __builtin_amdgcn_mfma_f32_16x16x32_bf16(av, b1, acc1, 0, 0, 0);
        }
        __builtin_amdgcn_sched_barrier(0);
        slot = (slot >= 2) ? 0 : slot + 1;
    }

    // epilogue: pre-scaled direct stores (each output element written once)
    #pragma unroll
    for (int r = 0; r < 4; r++) {
        const int row = rt * 16 + fq * 4 + r;
        float* op = out + ((size_t)(b * N_ + row)) * C_;
        op[cgp * 16 + fr]      = dsc[r] * acc0[r];
        op[cgp * 16 + 16 + fr] = dsc[r] * acc1[r];
    }
}

extern "C" void kernel_launch(void* const* d_in, const int* in_sizes, int n_in,
                              void* d_out, int out_size, void* d_ws, size_t ws_size,
                              hipStream_t stream)
{
    const float* x   = (const float*)d_in[0];
    const float* W   = (const float*)d_in[1];
    const float* U   = (const float*)d_in[2];
    const float* wsc = (const float*)d_in[3];
    float* out = (float*)d_out;

    // workspace: K0f (bf16, 128 MiB) | deg (fp32, 64 KiB) | xdTf (bf16, 2 MiB)
    unsigned short* K0  = (unsigned short*)d_ws;
    float*          deg = (float*)((char*)d_ws + (size_t)B_ * N_ * N_ * 2);
    unsigned short* xdT = (unsigned short*)((char*)deg + (size_t)B_ * N_ * 4);

    hipMemsetAsync(deg, 0, (size_t)B_ * N_ * sizeof(float), stream);
    hipLaunchKernelGGL(k_pass1, dim3(2080), dim3(256), 0, stream, W, U, K0, deg);
    hipLaunchKernelGGL(k_xdT,  dim3(64, 4),   dim3(256), 0, stream, x, deg, xdT);
    hipLaunchKernelGGL(k_gemm, dim3(128, 4),  dim3(256), 0, stream, K0, xdT, deg, wsc, out);
}